// Round 12
// baseline (455.135 us; speedup 1.0000x reference)
//
#include <hip/hip_runtime.h>
#include <hip/hip_bf16.h>

#define NNODES 50000
#define NEDGES 800000
#define DF 128
#define KW 1152                // K per branch: 128 silu + 1024 spline (native order)
#define EPS 0.001f

typedef __bf16 bf16x8 __attribute__((ext_vector_type(8)));
typedef float  f32x4  __attribute__((ext_vector_type(4)));
typedef unsigned long ulongx2 __attribute__((ext_vector_type(2)));

// async global->LDS, 16B per lane; LDS dest = wave-uniform base + lane*16 (linear)
#define GLOAD16(g, l) __builtin_amdgcn_global_load_lds( \
    (const __attribute__((address_space(1))) unsigned int*)(g), \
    (__attribute__((address_space(3))) unsigned int*)(l), 16, 0, 0)

// ---- fused prep: cast_x + deg_count (blocks 0..3124) | build_wt (3125..4276) --
__global__ void prep_fused(const float* __restrict__ x, const int* __restrict__ ei,
                           const float* __restrict__ bwl, const float* __restrict__ swl,
                           const float* __restrict__ bwc, const float* __restrict__ swc,
                           __bf16* __restrict__ xb, int* __restrict__ deg,
                           __bf16* __restrict__ wtl, __bf16* __restrict__ wtc) {
    const int bid = blockIdx.x;
    if (bid < 3125) {
        int i = bid * 256 + threadIdx.x;           // 0..799999
        f32x4 a = ((const f32x4*)x)[2 * i];
        f32x4 b = ((const f32x4*)x)[2 * i + 1];
        bf16x8 o;
        o[0] = (__bf16)a[0]; o[1] = (__bf16)a[1]; o[2] = (__bf16)a[2]; o[3] = (__bf16)a[3];
        o[4] = (__bf16)b[0]; o[5] = (__bf16)b[1]; o[6] = (__bf16)b[2]; o[7] = (__bf16)b[3];
        ((bf16x8*)xb)[i] = o;
        atomicAdd(&deg[ei[NEDGES + i]], 1);
    } else {
        int idx = (bid - 3125) * 256 + threadIdx.x;    // 0..294911
        int half = idx / (DF * KW);                    // 0 = L, 1 = C
        int gid  = idx - half * (DF * KW);
        const float* bw = half ? bwc : bwl;
        const float* sw = half ? swc : swl;
        __bf16*      wt = half ? wtc : wtl;
        int o = gid / KW;
        int k = gid - o * KW;
        float v = (k < 128) ? bw[o * DF + k] : sw[o * 1024 + (k - 128)];
        wt[gid] = (__bf16)v;
    }
}

// ---- single-block exclusive scan: deg[50000] -> rowptr (replaces 3 kernels) --
// 1024 threads x 49 elems (50176 >= 50000). Per-thread segment sum, 10-step
// Hillis-Steele block scan, segment re-walk writing rowptr. 400KB via one CU
// (L2-hot on 2nd pass) ~ old 3-kernel chain's work, minus 2 launch gaps.
__global__ __launch_bounds__(1024) void scan_all(const int* __restrict__ deg,
                                                 int* __restrict__ rowptr) {
    __shared__ int buf[1024];
    const int t = threadIdx.x;
    const int i0 = t * 49;
    int s = 0;
    for (int j = 0; j < 49; ++j) {
        int i = i0 + j;
        s += (i < NNODES) ? deg[i] : 0;
    }
    buf[t] = s;
    __syncthreads();
    for (int off = 1; off < 1024; off <<= 1) {
        int v = (t >= off) ? buf[t - off] : 0;
        __syncthreads();
        buf[t] += v;
        __syncthreads();
    }
    int run = buf[t] - s;                  // exclusive prefix of this segment
    for (int j = 0; j < 49; ++j) {
        int i = i0 + j;
        if (i < NNODES) {
            rowptr[i] = run;
            run += deg[i];
        }
    }
    if (t == 1023) rowptr[NNODES] = buf[1023];
}

__global__ void fill_csr(const int* __restrict__ ei, const int* __restrict__ deg,
                         const int* __restrict__ rowptr, int* __restrict__ cnt,
                         int* __restrict__ esrc, float* __restrict__ ew) {
    int e = blockIdx.x * 256 + threadIdx.x;
    if (e >= NEDGES) return;
    int s = ei[e];
    int d = ei[NEDGES + e];
    float w = rsqrtf((float)(deg[s] + 1)) * rsqrtf((float)(deg[d] + 1));
    int p = rowptr[d] + atomicAdd(&cnt[d], 1);
    esrc[p] = s;
    ew[p] = w;
}

// ---- aggregation: 16-lane group per node, bf16x8 (16B) loads ----------------
__global__ __launch_bounds__(256) void agg_gather(
        const int* __restrict__ rowptr, const int* __restrict__ esrc,
        const float* __restrict__ ew, const __bf16* __restrict__ hb,
        __bf16* __restrict__ aggb) {
    const int tid = blockIdx.x * 256 + threadIdx.x;
    const int n = tid >> 4;
    const int l = tid & 15;
    if (n >= NNODES) return;
    int p  = rowptr[n];
    const int pe = rowptr[n + 1];
    float acc[8] = {};
    int   cs0, cs1, cs2, cs3;
    float cw0, cw1, cw2, cw3;
    bool have = (p + 3 < pe);
    if (have) {
        cs0 = esrc[p]; cs1 = esrc[p + 1]; cs2 = esrc[p + 2]; cs3 = esrc[p + 3];
        cw0 = ew[p];   cw1 = ew[p + 1];   cw2 = ew[p + 2];   cw3 = ew[p + 3];
    }
    while (have) {
        int np = p + 4;
        bool nh = (np + 3 < pe);
        int   ns0 = 0, ns1 = 0, ns2 = 0, ns3 = 0;
        float nw0 = 0, nw1 = 0, nw2 = 0, nw3 = 0;
        if (nh) {
            ns0 = esrc[np]; ns1 = esrc[np + 1]; ns2 = esrc[np + 2]; ns3 = esrc[np + 3];
            nw0 = ew[np];   nw1 = ew[np + 1];   nw2 = ew[np + 2];   nw3 = ew[np + 3];
        }
        bf16x8 v0 = *(const bf16x8*)(hb + (size_t)cs0 * DF + l * 8);
        bf16x8 v1 = *(const bf16x8*)(hb + (size_t)cs1 * DF + l * 8);
        bf16x8 v2 = *(const bf16x8*)(hb + (size_t)cs2 * DF + l * 8);
        bf16x8 v3 = *(const bf16x8*)(hb + (size_t)cs3 * DF + l * 8);
#pragma unroll
        for (int j = 0; j < 8; ++j)
            acc[j] += cw0 * (float)v0[j] + cw1 * (float)v1[j]
                    + cw2 * (float)v2[j] + cw3 * (float)v3[j];
        p = np;
        cs0 = ns0; cs1 = ns1; cs2 = ns2; cs3 = ns3;
        cw0 = nw0; cw1 = nw1; cw2 = nw2; cw3 = nw3;
        have = nh;
    }
    for (; p < pe; ++p) {
        int   s0 = esrc[p];
        float w0 = ew[p];
        bf16x8 v0 = *(const bf16x8*)(hb + (size_t)s0 * DF + l * 8);
#pragma unroll
        for (int j = 0; j < 8; ++j) acc[j] += w0 * (float)v0[j];
    }
    bf16x8 o;
#pragma unroll
    for (int j = 0; j < 8; ++j) o[j] = (__bf16)acc[j];
    *(bf16x8*)(aggb + (size_t)n * DF + l * 8) = o;
}

// ---- fused Euler step: out = h + EPS*(kanl(h) + kanc(agg)) -------------------
// R10 structure, byte-identical (best measured: 370.3 total).
__global__ __launch_bounds__(256, 4) void kan_step(
        const float* __restrict__ h,          // f32 state (epilogue read)
        const __bf16* __restrict__ xb,        // bf16 shadow of h (branch L)
        const __bf16* __restrict__ aggb,      // bf16 aggregate (branch C)
        const __bf16* __restrict__ wtl, const __bf16* __restrict__ wtc,
        float* __restrict__ out, __bf16* __restrict__ outb) {
    __shared__ __bf16 Bs[3][128 * 32];       // 3 x 8 KB ring, slot-swizzled rows
    __shared__ __bf16 Xs[64 * 128];          // 16 KB, swizzled 16B granules

    const int tid  = threadIdx.x;
    const int lane = tid & 63;
    const int w    = tid >> 6;               // wave -> rows [w*16, +16)
    const int q    = lane >> 4, l15 = lane & 15;
    const int n0   = blockIdx.x * 64;
    const int myrow = w * 16 + l15;
    const int msw   = myrow & 7;             // Xs swizzle key for this lane

    const int relrow = lane >> 2;
    const int slotx  = (lane & 3) ^ ((relrow >> 1) & 3);  // R10 bank swizzle
    const int r0 = w * 16 + relrow;
    const size_t gb0 = (size_t)r0 * KW + (size_t)slotx * 8;
    const size_t gb1 = gb0 + (size_t)64 * KW;
    const int bslot = (q ^ ((l15 >> 1) & 3)) * 8;   // elems

    const int xrow = tid >> 2, xseg = tid & 3;
    const bool xok = (n0 + xrow) < NNODES;
    const size_t xgoff = (size_t)(n0 + xrow) * DF + xseg * 32;

    f32x4 acc[8] = {};

    auto xs_write = [&](uint4 v0, uint4 v1, uint4 v2, uint4 v3) {
        const int gl = xrow * 16 + xseg * 4;
        const int sw = xrow & 7;
        *(uint4*)&Xs[(size_t)((gl + 0) ^ sw) * 8] = v0;
        *(uint4*)&Xs[(size_t)((gl + 1) ^ sw) * 8] = v1;
        *(uint4*)&Xs[(size_t)((gl + 2) ^ sw) * 8] = v2;
        *(uint4*)&Xs[(size_t)((gl + 3) ^ sw) * 8] = v3;
    };

    auto stageB = [&](int t2, int sb) {
        const __bf16* wtp = (t2 >= 36) ? wtc : wtl;
        const int k0 = ((t2 >= 36) ? t2 - 36 : t2) * 32;
        GLOAD16(wtp + gb0 + k0, &Bs[sb][(w * 16) * 32]);        // rows w*16..+16
        GLOAD16(wtp + gb1 + k0, &Bs[sb][(64 + w * 16) * 32]);   // rows 64+w*16..+16
    };

    auto spline_pack = [&](float x) -> bf16x8 {
        float f  = __builtin_fmaf(x, 2.5f, 5.5f);    // (x+2.2)/0.4
        float fi = floorf(f);
        int  idx = (int)fi;
        float u  = f - fi;
        float u2 = u * u, u3 = u2 * u;
        float om = 1.0f - u;
        float Wa = u3 * (1.0f / 6.0f);
        float Wb = (((-3.0f * u + 3.0f) * u + 3.0f) * u + 1.0f) * (1.0f / 6.0f);
        float Wc = ((3.0f * u - 6.0f) * u2 + 4.0f) * (1.0f / 6.0f);
        float Wd = om * om * om * (1.0f / 6.0f);
        unsigned long p =
              (unsigned long)__builtin_bit_cast(unsigned short, (__bf16)Wd)
            | ((unsigned long)__builtin_bit_cast(unsigned short, (__bf16)Wc) << 16)
            | ((unsigned long)__builtin_bit_cast(unsigned short, (__bf16)Wb) << 32)
            | ((unsigned long)__builtin_bit_cast(unsigned short, (__bf16)Wa) << 48);
        int tt = idx - 3;                            // slot of Wd in [0,8)
        unsigned long lo, hi;
        if (tt >= 0) {
            int s = (tt & 3) * 16;
            unsigned long sv = p << s;
            unsigned long cr = (p >> (63 - s)) >> 1; // == p>>(64-s), s==0 safe
            bool hh = tt >= 4;
            lo = hh ? 0ul : sv;
            hi = hh ? sv : cr;
            if (tt >= 8) { lo = 0; hi = 0; }
        } else {
            int s = (-tt) * 16;
            lo = (tt >= -3) ? (p >> (s & 63)) : 0ul;
            hi = 0;
        }
        ulongx2 r; r[0] = lo; r[1] = hi;
        return __builtin_bit_cast(bf16x8, r);
    };

    auto silu8 = [&](const __bf16* xs) -> bf16x8 {
        bf16x8 v = *(const bf16x8*)xs;
        bf16x8 o;
#pragma unroll
        for (int j = 0; j < 8; ++j) {
            float x = (float)v[j];
            o[j] = (__bf16)(x / (1.0f + __expf(-x)));
        }
        return o;
    };

    // ---- prologue: both x-tiles loaded now (aggb is ready at launch) ----
    uint4 a0 = {}, a1 = {}, a2 = {}, a3 = {};
    uint4 c0 = {}, c1 = {}, c2 = {}, c3 = {};
    if (xok) {
        const uint4* ga = (const uint4*)(xb + xgoff);
        a0 = ga[0]; a1 = ga[1]; a2 = ga[2]; a3 = ga[3];
        const uint4* gc = (const uint4*)(aggb + xgoff);
        c0 = gc[0]; c1 = gc[1]; c2 = gc[2]; c3 = gc[3];
    }
    xs_write(a0, a1, a2, a3);
    stageB(0, 0);
    stageB(1, 1);
    // "memory" clobber: full compiler memory barrier -> the aggb loads above
    // cannot sink past this point; also orders the Xs ds_writes.
    asm volatile("s_waitcnt lgkmcnt(0)" ::: "memory");

    auto body = [&](int t, int cb, int sb, bool doStage, bool last) {
        if (last) asm volatile("s_waitcnt vmcnt(0)" ::: "memory");
        else      asm volatile("s_waitcnt vmcnt(2)" ::: "memory");  // chunk t staged
        __builtin_amdgcn_s_barrier();
        __builtin_amdgcn_sched_barrier(0);   // nothing crosses the barrier

        if (t == 36) {                       // branch switch: restage x-tile
            xs_write(c0, c1, c2, c3);        // all branch-L Xs reads done (barrier)
            asm volatile("s_waitcnt lgkmcnt(0)" ::: "memory");
            __builtin_amdgcn_s_barrier();
            __builtin_amdgcn_sched_barrier(0);
        }

        if (doStage) stageB(t + 2, sb);      // overwrites buf[(t-1)%3]: safe

        const int ck = (t >= 36) ? t - 36 : t;
        bf16x8 a;
        if (ck < 4) {
            // silu: features [ck*32 + q*8, +8) -> granule myrow*16 + ck*4 + q
            const int g = (myrow * 16 + ck * 4 + q) ^ msw;
            a = silu8(&Xs[(size_t)g * 8]);
        } else {
            const int f = (ck - 4) * 4 + q;  // feature index
            const int g = (myrow * 16 + (f >> 3)) ^ msw;
            unsigned short u0 =
                *(const unsigned short*)&Xs[(size_t)g * 8 + (f & 7)];
            a = spline_pack(__builtin_bit_cast(float, (unsigned)u0 << 16));
        }

        bf16x8 bF[8];
#pragma unroll
        for (int nj = 0; nj < 8; ++nj)
            bF[nj] = *(const bf16x8*)&Bs[cb][(nj * 16 + l15) * 32 + bslot];
#pragma unroll
        for (int nj = 0; nj < 8; ++nj)
            acc[nj] = __builtin_amdgcn_mfma_f32_16x16x32_bf16(a, bF[nj], acc[nj], 0, 0, 0);
    };

    int cb = 0, sb = 2;
#pragma unroll 3
    for (int t = 0; t < 69; ++t) {
        body(t, cb, sb, true, false);
        cb = (cb == 2) ? 0 : cb + 1;
        sb = (sb == 2) ? 0 : sb + 1;
    }
    body(69, 0, 2, true,  false);            // stages chunk 71 -> buf 2
    body(70, 1, 0, false, false);            // vmcnt(2): chunk 70 ready
    body(71, 2, 0, false, true);             // vmcnt(0): final chunk

    // epilogue: Euler; D layout row = q*4+r, col = l15 (m89-verified)
    const bool wxb = (outb != nullptr);      // uniform; final step skips shadow
#pragma unroll
    for (int nj = 0; nj < 8; ++nj) {
#pragma unroll
        for (int r = 0; r < 4; ++r) {
            int row = n0 + w * 16 + q * 4 + r;
            int col = nj * 16 + l15;
            if (row < NNODES) {
                size_t idx = (size_t)row * DF + col;
                float v = h[idx] + EPS * acc[nj][r];
                out[idx] = v;
                if (wxb) outb[idx] = (__bf16)v;
            }
        }
    }
}

extern "C" void kernel_launch(void* const* d_in, const int* in_sizes, int n_in,
                              void* d_out, int out_size, void* d_ws, size_t ws_size,
                              hipStream_t stream) {
    const float* x   = (const float*)d_in[0];
    const int*   ei  = (const int*)d_in[1];     // edge_index [2,E] int32
    const float* bwl = (const float*)d_in[2];
    const float* swl = (const float*)d_in[3];
    const float* bwc = (const float*)d_in[4];
    const float* swc = (const float*)d_in[5];
    float* out = (float*)d_out;

    char* ws = (char*)d_ws;
    int*    deg    = (int*)  (ws + 0);            //   200,000
    int*    cnt    = (int*)  (ws + 200000);       //   200,000 (adjacent: single memset)
    int*    rowptr = (int*)  (ws + 400000);       //   200,004
    int*    esrc   = (int*)  (ws + 601728);       // 3,200,000
    float*  ew     = (float*)(ws + 3801728);      // 3,200,000
    __bf16* xb     = (__bf16*)(ws + 7001728);     // 12,800,000
    __bf16* aggb   = (__bf16*)(ws + 19801728);    // 12,800,000
    __bf16* wtl    = (__bf16*)(ws + 32601728);    //    294,912
    __bf16* wtc    = (__bf16*)(ws + 32896640);    //    294,912  (total ~33.2 MB)

    (void)hipMemsetAsync(deg, 0, 400000, stream);       // deg + cnt
    prep_fused<<<4277, 256, 0, stream>>>(x, ei, bwl, swl, bwc, swc, xb, deg, wtl, wtc);
    scan_all<<<1, 1024, 0, stream>>>(deg, rowptr);
    fill_csr<<<3125, 256, 0, stream>>>(ei, deg, rowptr, cnt, esrc, ew);

    const int gemm_grid = (NNODES + 63) / 64;     // 782
    agg_gather<<<3125, 256, 0, stream>>>(rowptr, esrc, ew, xb, aggb);
    kan_step<<<gemm_grid, 256, 0, stream>>>(x, xb, aggb, wtl, wtc, out, xb);
    agg_gather<<<3125, 256, 0, stream>>>(rowptr, esrc, ew, xb, aggb);
    kan_step<<<gemm_grid, 256, 0, stream>>>(out, xb, aggb, wtl, wtc, out, (__bf16*)nullptr);
}

// Round 13
// 369.512 us; speedup vs baseline: 1.2317x; 1.2317x over previous
//
#include <hip/hip_runtime.h>
#include <hip/hip_bf16.h>

#define NNODES 50000
#define NEDGES 800000
#define DF 128
#define KW 1152                // K per branch: 128 silu + 1024 spline (native order)
#define EPS 0.001f
#define NB 196                 // scan blocks: 196*256 >= 50000

typedef __bf16 bf16x8 __attribute__((ext_vector_type(8)));
typedef __bf16 bf16x4 __attribute__((ext_vector_type(4)));
typedef float  f32x4  __attribute__((ext_vector_type(4)));
typedef unsigned long ulongx2 __attribute__((ext_vector_type(2)));

// async global->LDS, 16B per lane; LDS dest = wave-uniform base + lane*16 (linear)
#define GLOAD16(g, l) __builtin_amdgcn_global_load_lds( \
    (const __attribute__((address_space(1))) unsigned int*)(g), \
    (__attribute__((address_space(3))) unsigned int*)(l), 16, 0, 0)

// ---- fused prep: cast_x + deg_count (blocks 0..3124) | build_wt (3125..4276) --
__global__ void prep_fused(const float* __restrict__ x, const int* __restrict__ ei,
                           const float* __restrict__ bwl, const float* __restrict__ swl,
                           const float* __restrict__ bwc, const float* __restrict__ swc,
                           __bf16* __restrict__ xb, int* __restrict__ deg,
                           __bf16* __restrict__ wtl, __bf16* __restrict__ wtc) {
    const int bid = blockIdx.x;
    if (bid < 3125) {
        int i = bid * 256 + threadIdx.x;           // 0..799999
        f32x4 a = ((const f32x4*)x)[2 * i];
        f32x4 b = ((const f32x4*)x)[2 * i + 1];
        bf16x8 o;
        o[0] = (__bf16)a[0]; o[1] = (__bf16)a[1]; o[2] = (__bf16)a[2]; o[3] = (__bf16)a[3];
        o[4] = (__bf16)b[0]; o[5] = (__bf16)b[1]; o[6] = (__bf16)b[2]; o[7] = (__bf16)b[3];
        ((bf16x8*)xb)[i] = o;
        atomicAdd(&deg[ei[NEDGES + i]], 1);
    } else {
        int idx = (bid - 3125) * 256 + threadIdx.x;    // 0..294911
        int half = idx / (DF * KW);                    // 0 = L, 1 = C
        int gid  = idx - half * (DF * KW);
        const float* bw = half ? bwc : bwl;
        const float* sw = half ? swc : swl;
        __bf16*      wt = half ? wtc : wtl;
        int o = gid / KW;
        int k = gid - o * KW;
        float v = (k < 128) ? bw[o * DF + k] : sw[o * 1024 + (k - 128)];
        wt[gid] = (__bf16)v;
    }
}

// ---------------- CSR build ----------------
__global__ void scan_part(const int* __restrict__ deg, int* __restrict__ bsum) {
    __shared__ int red[256];
    int t = threadIdx.x;
    int i = blockIdx.x * 256 + t;
    red[t] = (i < NNODES) ? deg[i] : 0;
    __syncthreads();
    for (int off = 128; off > 0; off >>= 1) {
        if (t < off) red[t] += red[t + off];
        __syncthreads();
    }
    if (t == 0) bsum[blockIdx.x] = red[0];
}

__global__ void scan_bsum(const int* __restrict__ bsum, int* __restrict__ boff) {
    __shared__ int buf[256];
    int t = threadIdx.x;
    int v = (t < NB) ? bsum[t] : 0;
    buf[t] = v;
    __syncthreads();
    for (int off = 1; off < 256; off <<= 1) {
        int x = (t >= off) ? buf[t - off] : 0;
        __syncthreads();
        buf[t] += x;
        __syncthreads();
    }
    if (t <= NB) boff[t] = buf[t] - ((t < NB) ? bsum[t] : 0);   // exclusive; boff[NB]=total
}

__global__ void scan_final(const int* __restrict__ deg, const int* __restrict__ boff,
                           int* __restrict__ rowptr) {
    __shared__ int buf[256];
    int t = threadIdx.x;
    int i = blockIdx.x * 256 + t;
    int v = (i < NNODES) ? deg[i] : 0;
    buf[t] = v;
    __syncthreads();
    for (int off = 1; off < 256; off <<= 1) {
        int x = (t >= off) ? buf[t - off] : 0;
        __syncthreads();
        buf[t] += x;
        __syncthreads();
    }
    if (i < NNODES) rowptr[i] = buf[t] - v + boff[blockIdx.x];
    if (blockIdx.x == 0 && t == 0) rowptr[NNODES] = boff[NB];
}

__global__ void fill_csr(const int* __restrict__ ei, const int* __restrict__ deg,
                         const int* __restrict__ rowptr, int* __restrict__ cnt,
                         int* __restrict__ esrc, float* __restrict__ ew) {
    int e = blockIdx.x * 256 + threadIdx.x;
    if (e >= NEDGES) return;
    int s = ei[e];
    int d = ei[NEDGES + e];
    float w = rsqrtf((float)(deg[s] + 1)) * rsqrtf((float)(deg[d] + 1));
    int p = rowptr[d] + atomicAdd(&cnt[d], 1);
    esrc[p] = s;
    ew[p] = w;
}

// ---- aggregation: 16-lane group per node, bf16x8 (16B) loads ----------------
__global__ __launch_bounds__(256) void agg_gather(
        const int* __restrict__ rowptr, const int* __restrict__ esrc,
        const float* __restrict__ ew, const __bf16* __restrict__ hb,
        __bf16* __restrict__ aggb) {
    const int tid = blockIdx.x * 256 + threadIdx.x;
    const int n = tid >> 4;
    const int l = tid & 15;
    if (n >= NNODES) return;
    int p  = rowptr[n];
    const int pe = rowptr[n + 1];
    float acc[8] = {};
    int   cs0, cs1, cs2, cs3;
    float cw0, cw1, cw2, cw3;
    bool have = (p + 3 < pe);
    if (have) {
        cs0 = esrc[p]; cs1 = esrc[p + 1]; cs2 = esrc[p + 2]; cs3 = esrc[p + 3];
        cw0 = ew[p];   cw1 = ew[p + 1];   cw2 = ew[p + 2];   cw3 = ew[p + 3];
    }
    while (have) {
        int np = p + 4;
        bool nh = (np + 3 < pe);
        int   ns0 = 0, ns1 = 0, ns2 = 0, ns3 = 0;
        float nw0 = 0, nw1 = 0, nw2 = 0, nw3 = 0;
        if (nh) {
            ns0 = esrc[np]; ns1 = esrc[np + 1]; ns2 = esrc[np + 2]; ns3 = esrc[np + 3];
            nw0 = ew[np];   nw1 = ew[np + 1];   nw2 = ew[np + 2];   nw3 = ew[np + 3];
        }
        bf16x8 v0 = *(const bf16x8*)(hb + (size_t)cs0 * DF + l * 8);
        bf16x8 v1 = *(const bf16x8*)(hb + (size_t)cs1 * DF + l * 8);
        bf16x8 v2 = *(const bf16x8*)(hb + (size_t)cs2 * DF + l * 8);
        bf16x8 v3 = *(const bf16x8*)(hb + (size_t)cs3 * DF + l * 8);
#pragma unroll
        for (int j = 0; j < 8; ++j)
            acc[j] += cw0 * (float)v0[j] + cw1 * (float)v1[j]
                    + cw2 * (float)v2[j] + cw3 * (float)v3[j];
        p = np;
        cs0 = ns0; cs1 = ns1; cs2 = ns2; cs3 = ns3;
        cw0 = nw0; cw1 = nw1; cw2 = nw2; cw3 = nw3;
        have = nh;
    }
    for (; p < pe; ++p) {
        int   s0 = esrc[p];
        float w0 = ew[p];
        bf16x8 v0 = *(const bf16x8*)(hb + (size_t)s0 * DF + l * 8);
#pragma unroll
        for (int j = 0; j < 8; ++j) acc[j] += w0 * (float)v0[j];
    }
    bf16x8 o;
#pragma unroll
    for (int j = 0; j < 8; ++j) o[j] = (__bf16)acc[j];
    *(bf16x8*)(aggb + (size_t)n * DF + l * 8) = o;
}

// ---- fused Euler step: out = h + EPS*(kanl(h) + kanc(agg)) -------------------
// R10 structure, byte-identical (best measured: 370.3 total).
__global__ __launch_bounds__(256, 4) void kan_step(
        const float* __restrict__ h,          // f32 state (epilogue read)
        const __bf16* __restrict__ xb,        // bf16 shadow of h (branch L)
        const __bf16* __restrict__ aggb,      // bf16 aggregate (branch C)
        const __bf16* __restrict__ wtl, const __bf16* __restrict__ wtc,
        float* __restrict__ out, __bf16* __restrict__ outb) {
    __shared__ __bf16 Bs[3][128 * 32];       // 3 x 8 KB ring, slot-swizzled rows
    __shared__ __bf16 Xs[64 * 128];          // 16 KB, swizzled 16B granules

    const int tid  = threadIdx.x;
    const int lane = tid & 63;
    const int w    = tid >> 6;               // wave -> rows [w*16, +16)
    const int q    = lane >> 4, l15 = lane & 15;
    const int n0   = blockIdx.x * 64;
    const int myrow = w * 16 + l15;
    const int msw   = myrow & 7;             // Xs swizzle key for this lane

    const int relrow = lane >> 2;
    const int slotx  = (lane & 3) ^ ((relrow >> 1) & 3);  // R10 bank swizzle
    const int r0 = w * 16 + relrow;
    const size_t gb0 = (size_t)r0 * KW + (size_t)slotx * 8;
    const size_t gb1 = gb0 + (size_t)64 * KW;
    const int bslot = (q ^ ((l15 >> 1) & 3)) * 8;   // elems

    const int xrow = tid >> 2, xseg = tid & 3;
    const bool xok = (n0 + xrow) < NNODES;
    const size_t xgoff = (size_t)(n0 + xrow) * DF + xseg * 32;

    f32x4 acc[8] = {};

    auto xs_write = [&](uint4 v0, uint4 v1, uint4 v2, uint4 v3) {
        const int gl = xrow * 16 + xseg * 4;
        const int sw = xrow & 7;
        *(uint4*)&Xs[(size_t)((gl + 0) ^ sw) * 8] = v0;
        *(uint4*)&Xs[(size_t)((gl + 1) ^ sw) * 8] = v1;
        *(uint4*)&Xs[(size_t)((gl + 2) ^ sw) * 8] = v2;
        *(uint4*)&Xs[(size_t)((gl + 3) ^ sw) * 8] = v3;
    };

    auto stageB = [&](int t2, int sb) {
        const __bf16* wtp = (t2 >= 36) ? wtc : wtl;
        const int k0 = ((t2 >= 36) ? t2 - 36 : t2) * 32;
        GLOAD16(wtp + gb0 + k0, &Bs[sb][(w * 16) * 32]);        // rows w*16..+16
        GLOAD16(wtp + gb1 + k0, &Bs[sb][(64 + w * 16) * 32]);   // rows 64+w*16..+16
    };

    auto spline_pack = [&](float x) -> bf16x8 {
        float f  = __builtin_fmaf(x, 2.5f, 5.5f);    // (x+2.2)/0.4
        float fi = floorf(f);
        int  idx = (int)fi;
        float u  = f - fi;
        float u2 = u * u, u3 = u2 * u;
        float om = 1.0f - u;
        float Wa = u3 * (1.0f / 6.0f);
        float Wb = (((-3.0f * u + 3.0f) * u + 3.0f) * u + 1.0f) * (1.0f / 6.0f);
        float Wc = ((3.0f * u - 6.0f) * u2 + 4.0f) * (1.0f / 6.0f);
        float Wd = om * om * om * (1.0f / 6.0f);
        unsigned long p =
              (unsigned long)__builtin_bit_cast(unsigned short, (__bf16)Wd)
            | ((unsigned long)__builtin_bit_cast(unsigned short, (__bf16)Wc) << 16)
            | ((unsigned long)__builtin_bit_cast(unsigned short, (__bf16)Wb) << 32)
            | ((unsigned long)__builtin_bit_cast(unsigned short, (__bf16)Wa) << 48);
        int tt = idx - 3;                            // slot of Wd in [0,8)
        unsigned long lo, hi;
        if (tt >= 0) {
            int s = (tt & 3) * 16;
            unsigned long sv = p << s;
            unsigned long cr = (p >> (63 - s)) >> 1; // == p>>(64-s), s==0 safe
            bool hh = tt >= 4;
            lo = hh ? 0ul : sv;
            hi = hh ? sv : cr;
            if (tt >= 8) { lo = 0; hi = 0; }
        } else {
            int s = (-tt) * 16;
            lo = (tt >= -3) ? (p >> (s & 63)) : 0ul;
            hi = 0;
        }
        ulongx2 r; r[0] = lo; r[1] = hi;
        return __builtin_bit_cast(bf16x8, r);
    };

    auto silu8 = [&](const __bf16* xs) -> bf16x8 {
        bf16x8 v = *(const bf16x8*)xs;
        bf16x8 o;
#pragma unroll
        for (int j = 0; j < 8; ++j) {
            float x = (float)v[j];
            o[j] = (__bf16)(x / (1.0f + __expf(-x)));
        }
        return o;
    };

    // ---- prologue: both x-tiles loaded now (aggb is ready at launch) ----
    uint4 a0 = {}, a1 = {}, a2 = {}, a3 = {};
    uint4 c0 = {}, c1 = {}, c2 = {}, c3 = {};
    if (xok) {
        const uint4* ga = (const uint4*)(xb + xgoff);
        a0 = ga[0]; a1 = ga[1]; a2 = ga[2]; a3 = ga[3];
        const uint4* gc = (const uint4*)(aggb + xgoff);
        c0 = gc[0]; c1 = gc[1]; c2 = gc[2]; c3 = gc[3];
    }
    xs_write(a0, a1, a2, a3);
    stageB(0, 0);
    stageB(1, 1);
    // "memory" clobber: full compiler memory barrier -> the aggb loads above
    // cannot sink past this point; also orders the Xs ds_writes.
    asm volatile("s_waitcnt lgkmcnt(0)" ::: "memory");

    auto body = [&](int t, int cb, int sb, bool doStage, bool last) {
        if (last) asm volatile("s_waitcnt vmcnt(0)" ::: "memory");
        else      asm volatile("s_waitcnt vmcnt(2)" ::: "memory");  // chunk t staged
        __builtin_amdgcn_s_barrier();
        __builtin_amdgcn_sched_barrier(0);   // nothing crosses the barrier

        if (t == 36) {                       // branch switch: restage x-tile
            xs_write(c0, c1, c2, c3);        // all branch-L Xs reads done (barrier)
            asm volatile("s_waitcnt lgkmcnt(0)" ::: "memory");
            __builtin_amdgcn_s_barrier();
            __builtin_amdgcn_sched_barrier(0);
        }

        if (doStage) stageB(t + 2, sb);      // overwrites buf[(t-1)%3]: safe

        const int ck = (t >= 36) ? t - 36 : t;
        bf16x8 a;
        if (ck < 4) {
            // silu: features [ck*32 + q*8, +8) -> granule myrow*16 + ck*4 + q
            const int g = (myrow * 16 + ck * 4 + q) ^ msw;
            a = silu8(&Xs[(size_t)g * 8]);
        } else {
            const int f = (ck - 4) * 4 + q;  // feature index
            const int g = (myrow * 16 + (f >> 3)) ^ msw;
            unsigned short u0 =
                *(const unsigned short*)&Xs[(size_t)g * 8 + (f & 7)];
            a = spline_pack(__builtin_bit_cast(float, (unsigned)u0 << 16));
        }

        bf16x8 bF[8];
#pragma unroll
        for (int nj = 0; nj < 8; ++nj)
            bF[nj] = *(const bf16x8*)&Bs[cb][(nj * 16 + l15) * 32 + bslot];
#pragma unroll
        for (int nj = 0; nj < 8; ++nj)
            acc[nj] = __builtin_amdgcn_mfma_f32_16x16x32_bf16(a, bF[nj], acc[nj], 0, 0, 0);
    };

    int cb = 0, sb = 2;
#pragma unroll 3
    for (int t = 0; t < 69; ++t) {
        body(t, cb, sb, true, false);
        cb = (cb == 2) ? 0 : cb + 1;
        sb = (sb == 2) ? 0 : sb + 1;
    }
    body(69, 0, 2, true,  false);            // stages chunk 71 -> buf 2
    body(70, 1, 0, false, false);            // vmcnt(2): chunk 70 ready
    body(71, 2, 0, false, true);             // vmcnt(0): final chunk

    // epilogue: Euler; D layout row = q*4+r, col = l15 (m89-verified)
    const bool wxb = (outb != nullptr);      // uniform; final step skips shadow
#pragma unroll
    for (int nj = 0; nj < 8; ++nj) {
#pragma unroll
        for (int r = 0; r < 4; ++r) {
            int row = n0 + w * 16 + q * 4 + r;
            int col = nj * 16 + l15;
            if (row < NNODES) {
                size_t idx = (size_t)row * DF + col;
                float v = h[idx] + EPS * acc[nj][r];
                out[idx] = v;
                if (wxb) outb[idx] = (__bf16)v;
            }
        }
    }
}

extern "C" void kernel_launch(void* const* d_in, const int* in_sizes, int n_in,
                              void* d_out, int out_size, void* d_ws, size_t ws_size,
                              hipStream_t stream) {
    const float* x   = (const float*)d_in[0];
    const int*   ei  = (const int*)d_in[1];     // edge_index [2,E] int32
    const float* bwl = (const float*)d_in[2];
    const float* swl = (const float*)d_in[3];
    const float* bwc = (const float*)d_in[4];
    const float* swc = (const float*)d_in[5];
    float* out = (float*)d_out;

    char* ws = (char*)d_ws;
    int*    deg    = (int*)  (ws + 0);            //   200,000
    int*    cnt    = (int*)  (ws + 200000);       //   200,000 (adjacent: single memset)
    int*    rowptr = (int*)  (ws + 400000);       //   200,004
    int*    bsum   = (int*)  (ws + 600064);       //       784
    int*    boff   = (int*)  (ws + 600896);       //       788
    int*    esrc   = (int*)  (ws + 601728);       // 3,200,000
    float*  ew     = (float*)(ws + 3801728);      // 3,200,000
    __bf16* xb     = (__bf16*)(ws + 7001728);     // 12,800,000
    __bf16* aggb   = (__bf16*)(ws + 19801728);    // 12,800,000
    __bf16* wtl    = (__bf16*)(ws + 32601728);    //    294,912
    __bf16* wtc    = (__bf16*)(ws + 32896640);    //    294,912  (total ~33.2 MB)

    (void)hipMemsetAsync(deg, 0, 400000, stream);       // deg + cnt
    prep_fused<<<4277, 256, 0, stream>>>(x, ei, bwl, swl, bwc, swc, xb, deg, wtl, wtc);
    scan_part<<<NB, 256, 0, stream>>>(deg, bsum);
    scan_bsum<<<1, 256, 0, stream>>>(bsum, boff);
    scan_final<<<NB, 256, 0, stream>>>(deg, boff, rowptr);
    fill_csr<<<3125, 256, 0, stream>>>(ei, deg, rowptr, cnt, esrc, ew);

    const int gemm_grid = (NNODES + 63) / 64;     // 782
    agg_gather<<<3125, 256, 0, stream>>>(rowptr, esrc, ew, xb, aggb);
    kan_step<<<gemm_grid, 256, 0, stream>>>(x, xb, aggb, wtl, wtc, out, xb);
    agg_gather<<<3125, 256, 0, stream>>>(rowptr, esrc, ew, xb, aggb);
    kan_step<<<gemm_grid, 256, 0, stream>>>(out, xb, aggb, wtl, wtc, out, (__bf16*)nullptr);
}

// Round 14
// 364.004 us; speedup vs baseline: 1.2504x; 1.0151x over previous
//
#include <hip/hip_runtime.h>
#include <hip/hip_bf16.h>

#define NNODES 50000
#define NEDGES 800000
#define DF 128
#define KW 1152                // K per branch: 128 silu + 1024 spline (native order)
#define EPS 0.001f
#define NB 196                 // scan blocks: 196*256 >= 50000

typedef __bf16 bf16x8 __attribute__((ext_vector_type(8)));
typedef __bf16 bf16x4 __attribute__((ext_vector_type(4)));
typedef float  f32x4  __attribute__((ext_vector_type(4)));
typedef unsigned long ulongx2 __attribute__((ext_vector_type(2)));

// async global->LDS, 16B per lane; LDS dest = wave-uniform base + lane*16 (linear)
#define GLOAD16(g, l) __builtin_amdgcn_global_load_lds( \
    (const __attribute__((address_space(1))) unsigned int*)(g), \
    (__attribute__((address_space(3))) unsigned int*)(l), 16, 0, 0)

// ---- fused prep: cast_x + deg_count (blocks 0..3124) | build_wt (3125..4276) --
__global__ void prep_fused(const float* __restrict__ x, const int* __restrict__ ei,
                           const float* __restrict__ bwl, const float* __restrict__ swl,
                           const float* __restrict__ bwc, const float* __restrict__ swc,
                           __bf16* __restrict__ xb, int* __restrict__ deg,
                           __bf16* __restrict__ wtl, __bf16* __restrict__ wtc) {
    const int bid = blockIdx.x;
    if (bid < 3125) {
        int i = bid * 256 + threadIdx.x;           // 0..799999
        f32x4 a = ((const f32x4*)x)[2 * i];
        f32x4 b = ((const f32x4*)x)[2 * i + 1];
        bf16x8 o;
        o[0] = (__bf16)a[0]; o[1] = (__bf16)a[1]; o[2] = (__bf16)a[2]; o[3] = (__bf16)a[3];
        o[4] = (__bf16)b[0]; o[5] = (__bf16)b[1]; o[6] = (__bf16)b[2]; o[7] = (__bf16)b[3];
        ((bf16x8*)xb)[i] = o;
        atomicAdd(&deg[ei[NEDGES + i]], 1);
    } else {
        int idx = (bid - 3125) * 256 + threadIdx.x;    // 0..294911
        int half = idx / (DF * KW);                    // 0 = L, 1 = C
        int gid  = idx - half * (DF * KW);
        const float* bw = half ? bwc : bwl;
        const float* sw = half ? swc : swl;
        __bf16*      wt = half ? wtc : wtl;
        int o = gid / KW;
        int k = gid - o * KW;
        float v = (k < 128) ? bw[o * DF + k] : sw[o * 1024 + (k - 128)];
        wt[gid] = (__bf16)v;
    }
}

// ---------------- CSR build ----------------
__global__ void scan_part(const int* __restrict__ deg, int* __restrict__ bsum) {
    __shared__ int red[256];
    int t = threadIdx.x;
    int i = blockIdx.x * 256 + t;
    red[t] = (i < NNODES) ? deg[i] : 0;
    __syncthreads();
    for (int off = 128; off > 0; off >>= 1) {
        if (t < off) red[t] += red[t + off];
        __syncthreads();
    }
    if (t == 0) bsum[blockIdx.x] = red[0];
}

// scan_final with the bsum-prefix folded in: every block redundantly scans the
// 196-entry bsum array (784 B, L2-hot) in LDS and takes its own exclusive
// offset. Replaces the old scan_bsum + scan_final pair (saves 1 launch + gap).
__global__ void scan_final(const int* __restrict__ deg, const int* __restrict__ bsum,
                           int* __restrict__ rowptr) {
    __shared__ int buf[256];
    __shared__ int bpre[256];
    int t = threadIdx.x;
    int bv = (t < NB) ? bsum[t] : 0;
    bpre[t] = bv;
    __syncthreads();
    for (int off = 1; off < 256; off <<= 1) {
        int xv = (t >= off) ? bpre[t - off] : 0;
        __syncthreads();
        bpre[t] += xv;
        __syncthreads();
    }
    // bpre[t] = inclusive prefix of bsum; block b's exclusive offset = bpre[b]-bsum[b]
    int i = blockIdx.x * 256 + t;
    int v = (i < NNODES) ? deg[i] : 0;
    buf[t] = v;
    __syncthreads();
    for (int off = 1; off < 256; off <<= 1) {
        int xv = (t >= off) ? buf[t - off] : 0;
        __syncthreads();
        buf[t] += xv;
        __syncthreads();
    }
    int boffb = bpre[blockIdx.x] - ((blockIdx.x < NB) ? bsum[blockIdx.x] : 0);
    if (i < NNODES) rowptr[i] = buf[t] - v + boffb;
    if (blockIdx.x == 0 && t == 0) rowptr[NNODES] = bpre[NB - 1];   // total
}

__global__ void fill_csr(const int* __restrict__ ei, const int* __restrict__ deg,
                         const int* __restrict__ rowptr, int* __restrict__ cnt,
                         int* __restrict__ esrc, float* __restrict__ ew) {
    int e = blockIdx.x * 256 + threadIdx.x;
    if (e >= NEDGES) return;
    int s = ei[e];
    int d = ei[NEDGES + e];
    float w = rsqrtf((float)(deg[s] + 1)) * rsqrtf((float)(deg[d] + 1));
    int p = rowptr[d] + atomicAdd(&cnt[d], 1);
    esrc[p] = s;
    ew[p] = w;
}

// ---- aggregation: 16-lane group per node, bf16x8 (16B) loads ----------------
__global__ __launch_bounds__(256) void agg_gather(
        const int* __restrict__ rowptr, const int* __restrict__ esrc,
        const float* __restrict__ ew, const __bf16* __restrict__ hb,
        __bf16* __restrict__ aggb) {
    const int tid = blockIdx.x * 256 + threadIdx.x;
    const int n = tid >> 4;
    const int l = tid & 15;
    if (n >= NNODES) return;
    int p  = rowptr[n];
    const int pe = rowptr[n + 1];
    float acc[8] = {};
    int   cs0, cs1, cs2, cs3;
    float cw0, cw1, cw2, cw3;
    bool have = (p + 3 < pe);
    if (have) {
        cs0 = esrc[p]; cs1 = esrc[p + 1]; cs2 = esrc[p + 2]; cs3 = esrc[p + 3];
        cw0 = ew[p];   cw1 = ew[p + 1];   cw2 = ew[p + 2];   cw3 = ew[p + 3];
    }
    while (have) {
        int np = p + 4;
        bool nh = (np + 3 < pe);
        int   ns0 = 0, ns1 = 0, ns2 = 0, ns3 = 0;
        float nw0 = 0, nw1 = 0, nw2 = 0, nw3 = 0;
        if (nh) {
            ns0 = esrc[np]; ns1 = esrc[np + 1]; ns2 = esrc[np + 2]; ns3 = esrc[np + 3];
            nw0 = ew[np];   nw1 = ew[np + 1];   nw2 = ew[np + 2];   nw3 = ew[np + 3];
        }
        bf16x8 v0 = *(const bf16x8*)(hb + (size_t)cs0 * DF + l * 8);
        bf16x8 v1 = *(const bf16x8*)(hb + (size_t)cs1 * DF + l * 8);
        bf16x8 v2 = *(const bf16x8*)(hb + (size_t)cs2 * DF + l * 8);
        bf16x8 v3 = *(const bf16x8*)(hb + (size_t)cs3 * DF + l * 8);
#pragma unroll
        for (int j = 0; j < 8; ++j)
            acc[j] += cw0 * (float)v0[j] + cw1 * (float)v1[j]
                    + cw2 * (float)v2[j] + cw3 * (float)v3[j];
        p = np;
        cs0 = ns0; cs1 = ns1; cs2 = ns2; cs3 = ns3;
        cw0 = nw0; cw1 = nw1; cw2 = nw2; cw3 = nw3;
        have = nh;
    }
    for (; p < pe; ++p) {
        int   s0 = esrc[p];
        float w0 = ew[p];
        bf16x8 v0 = *(const bf16x8*)(hb + (size_t)s0 * DF + l * 8);
#pragma unroll
        for (int j = 0; j < 8; ++j) acc[j] += w0 * (float)v0[j];
    }
    bf16x8 o;
#pragma unroll
    for (int j = 0; j < 8; ++j) o[j] = (__bf16)acc[j];
    *(bf16x8*)(aggb + (size_t)n * DF + l * 8) = o;
}

// ---- fused Euler step: out = h + EPS*(kanl(h) + kanc(agg)) -------------------
// R10/R13 structure; only change: silu divide -> v_rcp_f32 (no -ffast-math, so
// x/(1+e) emitted the full IEEE div sequence ~9 VALU/elem; rcp = 2, and 1-ulp
// f32 rcp error is invisible at bf16 output precision).
__global__ __launch_bounds__(256, 4) void kan_step(
        const float* __restrict__ h,          // f32 state (epilogue read)
        const __bf16* __restrict__ xb,        // bf16 shadow of h (branch L)
        const __bf16* __restrict__ aggb,      // bf16 aggregate (branch C)
        const __bf16* __restrict__ wtl, const __bf16* __restrict__ wtc,
        float* __restrict__ out, __bf16* __restrict__ outb) {
    __shared__ __bf16 Bs[3][128 * 32];       // 3 x 8 KB ring, slot-swizzled rows
    __shared__ __bf16 Xs[64 * 128];          // 16 KB, swizzled 16B granules

    const int tid  = threadIdx.x;
    const int lane = tid & 63;
    const int w    = tid >> 6;               // wave -> rows [w*16, +16)
    const int q    = lane >> 4, l15 = lane & 15;
    const int n0   = blockIdx.x * 64;
    const int myrow = w * 16 + l15;
    const int msw   = myrow & 7;             // Xs swizzle key for this lane

    const int relrow = lane >> 2;
    const int slotx  = (lane & 3) ^ ((relrow >> 1) & 3);  // R10 bank swizzle
    const int r0 = w * 16 + relrow;
    const size_t gb0 = (size_t)r0 * KW + (size_t)slotx * 8;
    const size_t gb1 = gb0 + (size_t)64 * KW;
    const int bslot = (q ^ ((l15 >> 1) & 3)) * 8;   // elems

    const int xrow = tid >> 2, xseg = tid & 3;
    const bool xok = (n0 + xrow) < NNODES;
    const size_t xgoff = (size_t)(n0 + xrow) * DF + xseg * 32;

    f32x4 acc[8] = {};

    auto xs_write = [&](uint4 v0, uint4 v1, uint4 v2, uint4 v3) {
        const int gl = xrow * 16 + xseg * 4;
        const int sw = xrow & 7;
        *(uint4*)&Xs[(size_t)((gl + 0) ^ sw) * 8] = v0;
        *(uint4*)&Xs[(size_t)((gl + 1) ^ sw) * 8] = v1;
        *(uint4*)&Xs[(size_t)((gl + 2) ^ sw) * 8] = v2;
        *(uint4*)&Xs[(size_t)((gl + 3) ^ sw) * 8] = v3;
    };

    auto stageB = [&](int t2, int sb) {
        const __bf16* wtp = (t2 >= 36) ? wtc : wtl;
        const int k0 = ((t2 >= 36) ? t2 - 36 : t2) * 32;
        GLOAD16(wtp + gb0 + k0, &Bs[sb][(w * 16) * 32]);        // rows w*16..+16
        GLOAD16(wtp + gb1 + k0, &Bs[sb][(64 + w * 16) * 32]);   // rows 64+w*16..+16
    };

    auto spline_pack = [&](float x) -> bf16x8 {
        float f  = __builtin_fmaf(x, 2.5f, 5.5f);    // (x+2.2)/0.4
        float fi = floorf(f);
        int  idx = (int)fi;
        float u  = f - fi;
        float u2 = u * u, u3 = u2 * u;
        float om = 1.0f - u;
        float Wa = u3 * (1.0f / 6.0f);
        float Wb = (((-3.0f * u + 3.0f) * u + 3.0f) * u + 1.0f) * (1.0f / 6.0f);
        float Wc = ((3.0f * u - 6.0f) * u2 + 4.0f) * (1.0f / 6.0f);
        float Wd = om * om * om * (1.0f / 6.0f);
        unsigned long p =
              (unsigned long)__builtin_bit_cast(unsigned short, (__bf16)Wd)
            | ((unsigned long)__builtin_bit_cast(unsigned short, (__bf16)Wc) << 16)
            | ((unsigned long)__builtin_bit_cast(unsigned short, (__bf16)Wb) << 32)
            | ((unsigned long)__builtin_bit_cast(unsigned short, (__bf16)Wa) << 48);
        int tt = idx - 3;                            // slot of Wd in [0,8)
        unsigned long lo, hi;
        if (tt >= 0) {
            int s = (tt & 3) * 16;
            unsigned long sv = p << s;
            unsigned long cr = (p >> (63 - s)) >> 1; // == p>>(64-s), s==0 safe
            bool hh = tt >= 4;
            lo = hh ? 0ul : sv;
            hi = hh ? sv : cr;
            if (tt >= 8) { lo = 0; hi = 0; }
        } else {
            int s = (-tt) * 16;
            lo = (tt >= -3) ? (p >> (s & 63)) : 0ul;
            hi = 0;
        }
        ulongx2 r; r[0] = lo; r[1] = hi;
        return __builtin_bit_cast(bf16x8, r);
    };

    auto silu8 = [&](const __bf16* xs) -> bf16x8 {
        bf16x8 v = *(const bf16x8*)xs;
        bf16x8 o;
#pragma unroll
        for (int j = 0; j < 8; ++j) {
            float x = (float)v[j];
            float e = 1.0f + __expf(-x);
            o[j] = (__bf16)(x * __builtin_amdgcn_rcpf(e));   // 1-ulp rcp, bf16-safe
        }
        return o;
    };

    // ---- prologue: both x-tiles loaded now (aggb is ready at launch) ----
    uint4 a0 = {}, a1 = {}, a2 = {}, a3 = {};
    uint4 c0 = {}, c1 = {}, c2 = {}, c3 = {};
    if (xok) {
        const uint4* ga = (const uint4*)(xb + xgoff);
        a0 = ga[0]; a1 = ga[1]; a2 = ga[2]; a3 = ga[3];
        const uint4* gc = (const uint4*)(aggb + xgoff);
        c0 = gc[0]; c1 = gc[1]; c2 = gc[2]; c3 = gc[3];
    }
    xs_write(a0, a1, a2, a3);
    stageB(0, 0);
    stageB(1, 1);
    // "memory" clobber: full compiler memory barrier -> the aggb loads above
    // cannot sink past this point; also orders the Xs ds_writes.
    asm volatile("s_waitcnt lgkmcnt(0)" ::: "memory");

    auto body = [&](int t, int cb, int sb, bool doStage, bool last) {
        if (last) asm volatile("s_waitcnt vmcnt(0)" ::: "memory");
        else      asm volatile("s_waitcnt vmcnt(2)" ::: "memory");  // chunk t staged
        __builtin_amdgcn_s_barrier();
        __builtin_amdgcn_sched_barrier(0);   // nothing crosses the barrier

        if (t == 36) {                       // branch switch: restage x-tile
            xs_write(c0, c1, c2, c3);        // all branch-L Xs reads done (barrier)
            asm volatile("s_waitcnt lgkmcnt(0)" ::: "memory");
            __builtin_amdgcn_s_barrier();
            __builtin_amdgcn_sched_barrier(0);
        }

        if (doStage) stageB(t + 2, sb);      // overwrites buf[(t-1)%3]: safe

        const int ck = (t >= 36) ? t - 36 : t;
        bf16x8 a;
        if (ck < 4) {
            // silu: features [ck*32 + q*8, +8) -> granule myrow*16 + ck*4 + q
            const int g = (myrow * 16 + ck * 4 + q) ^ msw;
            a = silu8(&Xs[(size_t)g * 8]);
        } else {
            const int f = (ck - 4) * 4 + q;  // feature index
            const int g = (myrow * 16 + (f >> 3)) ^ msw;
            unsigned short u0 =
                *(const unsigned short*)&Xs[(size_t)g * 8 + (f & 7)];
            a = spline_pack(__builtin_bit_cast(float, (unsigned)u0 << 16));
        }

        bf16x8 bF[8];
#pragma unroll
        for (int nj = 0; nj < 8; ++nj)
            bF[nj] = *(const bf16x8*)&Bs[cb][(nj * 16 + l15) * 32 + bslot];
#pragma unroll
        for (int nj = 0; nj < 8; ++nj)
            acc[nj] = __builtin_amdgcn_mfma_f32_16x16x32_bf16(a, bF[nj], acc[nj], 0, 0, 0);
    };

    int cb = 0, sb = 2;
#pragma unroll 3
    for (int t = 0; t < 69; ++t) {
        body(t, cb, sb, true, false);
        cb = (cb == 2) ? 0 : cb + 1;
        sb = (sb == 2) ? 0 : sb + 1;
    }
    body(69, 0, 2, true,  false);            // stages chunk 71 -> buf 2
    body(70, 1, 0, false, false);            // vmcnt(2): chunk 70 ready
    body(71, 2, 0, false, true);             // vmcnt(0): final chunk

    // epilogue: Euler; D layout row = q*4+r, col = l15 (m89-verified)
    const bool wxb = (outb != nullptr);      // uniform; final step skips shadow
#pragma unroll
    for (int nj = 0; nj < 8; ++nj) {
#pragma unroll
        for (int r = 0; r < 4; ++r) {
            int row = n0 + w * 16 + q * 4 + r;
            int col = nj * 16 + l15;
            if (row < NNODES) {
                size_t idx = (size_t)row * DF + col;
                float v = h[idx] + EPS * acc[nj][r];
                out[idx] = v;
                if (wxb) outb[idx] = (__bf16)v;
            }
        }
    }
}

extern "C" void kernel_launch(void* const* d_in, const int* in_sizes, int n_in,
                              void* d_out, int out_size, void* d_ws, size_t ws_size,
                              hipStream_t stream) {
    const float* x   = (const float*)d_in[0];
    const int*   ei  = (const int*)d_in[1];     // edge_index [2,E] int32
    const float* bwl = (const float*)d_in[2];
    const float* swl = (const float*)d_in[3];
    const float* bwc = (const float*)d_in[4];
    const float* swc = (const float*)d_in[5];
    float* out = (float*)d_out;

    char* ws = (char*)d_ws;
    int*    deg    = (int*)  (ws + 0);            //   200,000
    int*    cnt    = (int*)  (ws + 200000);       //   200,000 (adjacent: single memset)
    int*    rowptr = (int*)  (ws + 400000);       //   200,004
    int*    bsum   = (int*)  (ws + 600064);       //       784
    int*    esrc   = (int*)  (ws + 601728);       // 3,200,000
    float*  ew     = (float*)(ws + 3801728);      // 3,200,000
    __bf16* xb     = (__bf16*)(ws + 7001728);     // 12,800,000
    __bf16* aggb   = (__bf16*)(ws + 19801728);    // 12,800,000
    __bf16* wtl    = (__bf16*)(ws + 32601728);    //    294,912
    __bf16* wtc    = (__bf16*)(ws + 32896640);    //    294,912  (total ~33.2 MB)

    (void)hipMemsetAsync(deg, 0, 400000, stream);       // deg + cnt
    prep_fused<<<4277, 256, 0, stream>>>(x, ei, bwl, swl, bwc, swc, xb, deg, wtl, wtc);
    scan_part<<<NB, 256, 0, stream>>>(deg, bsum);
    scan_final<<<NB, 256, 0, stream>>>(deg, bsum, rowptr);
    fill_csr<<<3125, 256, 0, stream>>>(ei, deg, rowptr, cnt, esrc, ew);

    const int gemm_grid = (NNODES + 63) / 64;     // 782
    agg_gather<<<3125, 256, 0, stream>>>(rowptr, esrc, ew, xb, aggb);
    kan_step<<<gemm_grid, 256, 0, stream>>>(x, xb, aggb, wtl, wtc, out, xb);
    agg_gather<<<3125, 256, 0, stream>>>(rowptr, esrc, ew, xb, aggb);
    kan_step<<<gemm_grid, 256, 0, stream>>>(out, xb, aggb, wtl, wtc, out, (__bf16*)nullptr);
}

// Round 15
// 360.419 us; speedup vs baseline: 1.2628x; 1.0099x over previous
//
#include <hip/hip_runtime.h>
#include <hip/hip_bf16.h>

#define NNODES 50000
#define NEDGES 800000
#define DF 128
#define KW 1152                // K per branch: 128 silu + 1024 spline (native order)
#define EPS 0.001f
#define NB 196                 // scan blocks: 196*256 >= 50000

typedef __bf16 bf16x8 __attribute__((ext_vector_type(8)));
typedef __bf16 bf16x4 __attribute__((ext_vector_type(4)));
typedef float  f32x4  __attribute__((ext_vector_type(4)));
typedef unsigned long ulongx2 __attribute__((ext_vector_type(2)));

// async global->LDS, 16B per lane; LDS dest = wave-uniform base + lane*16 (linear)
#define GLOAD16(g, l) __builtin_amdgcn_global_load_lds( \
    (const __attribute__((address_space(1))) unsigned int*)(g), \
    (__attribute__((address_space(3))) unsigned int*)(l), 16, 0, 0)

// ---- fused prep: cast_x + deg_count (blocks 0..3124) | build_wt (3125..4276) --
// Spline weights (k >= 128) pre-scaled by 1/6: the cubic B-spline basis carries
// a uniform 1/6 factor; folding it here lets kan_step's spline_pack use the
// unscaled polynomials (saves 4 VALU/pack on the dominant path). Exact
// refactoring: (W/6)*w == W*(w/6); silu region (k<128) untouched.
__global__ void prep_fused(const float* __restrict__ x, const int* __restrict__ ei,
                           const float* __restrict__ bwl, const float* __restrict__ swl,
                           const float* __restrict__ bwc, const float* __restrict__ swc,
                           __bf16* __restrict__ xb, int* __restrict__ deg,
                           __bf16* __restrict__ wtl, __bf16* __restrict__ wtc) {
    const int bid = blockIdx.x;
    if (bid < 3125) {
        int i = bid * 256 + threadIdx.x;           // 0..799999
        f32x4 a = ((const f32x4*)x)[2 * i];
        f32x4 b = ((const f32x4*)x)[2 * i + 1];
        bf16x8 o;
        o[0] = (__bf16)a[0]; o[1] = (__bf16)a[1]; o[2] = (__bf16)a[2]; o[3] = (__bf16)a[3];
        o[4] = (__bf16)b[0]; o[5] = (__bf16)b[1]; o[6] = (__bf16)b[2]; o[7] = (__bf16)b[3];
        ((bf16x8*)xb)[i] = o;
        atomicAdd(&deg[ei[NEDGES + i]], 1);
    } else {
        int idx = (bid - 3125) * 256 + threadIdx.x;    // 0..294911
        int half = idx / (DF * KW);                    // 0 = L, 1 = C
        int gid  = idx - half * (DF * KW);
        const float* bw = half ? bwc : bwl;
        const float* sw = half ? swc : swl;
        __bf16*      wt = half ? wtc : wtl;
        int o = gid / KW;
        int k = gid - o * KW;
        float v = (k < 128) ? bw[o * DF + k]
                            : sw[o * 1024 + (k - 128)] * (1.0f / 6.0f);
        wt[gid] = (__bf16)v;
    }
}

// ---------------- CSR build ----------------
__global__ void scan_part(const int* __restrict__ deg, int* __restrict__ bsum) {
    __shared__ int red[256];
    int t = threadIdx.x;
    int i = blockIdx.x * 256 + t;
    red[t] = (i < NNODES) ? deg[i] : 0;
    __syncthreads();
    for (int off = 128; off > 0; off >>= 1) {
        if (t < off) red[t] += red[t + off];
        __syncthreads();
    }
    if (t == 0) bsum[blockIdx.x] = red[0];
}

// scan_final with the bsum-prefix folded in: every block redundantly scans the
// 196-entry bsum array (784 B, L2-hot) in LDS and takes its own exclusive
// offset. Replaces the old scan_bsum + scan_final pair (saves 1 launch + gap).
__global__ void scan_final(const int* __restrict__ deg, const int* __restrict__ bsum,
                           int* __restrict__ rowptr) {
    __shared__ int buf[256];
    __shared__ int bpre[256];
    int t = threadIdx.x;
    int bv = (t < NB) ? bsum[t] : 0;
    bpre[t] = bv;
    __syncthreads();
    for (int off = 1; off < 256; off <<= 1) {
        int xv = (t >= off) ? bpre[t - off] : 0;
        __syncthreads();
        bpre[t] += xv;
        __syncthreads();
    }
    // bpre[t] = inclusive prefix of bsum; block b's exclusive offset = bpre[b]-bsum[b]
    int i = blockIdx.x * 256 + t;
    int v = (i < NNODES) ? deg[i] : 0;
    buf[t] = v;
    __syncthreads();
    for (int off = 1; off < 256; off <<= 1) {
        int xv = (t >= off) ? buf[t - off] : 0;
        __syncthreads();
        buf[t] += xv;
        __syncthreads();
    }
    int boffb = bpre[blockIdx.x] - ((blockIdx.x < NB) ? bsum[blockIdx.x] : 0);
    if (i < NNODES) rowptr[i] = buf[t] - v + boffb;
    if (blockIdx.x == 0 && t == 0) rowptr[NNODES] = bpre[NB - 1];   // total
}

__global__ void fill_csr(const int* __restrict__ ei, const int* __restrict__ deg,
                         const int* __restrict__ rowptr, int* __restrict__ cnt,
                         int* __restrict__ esrc, float* __restrict__ ew) {
    int e = blockIdx.x * 256 + threadIdx.x;
    if (e >= NEDGES) return;
    int s = ei[e];
    int d = ei[NEDGES + e];
    float w = rsqrtf((float)(deg[s] + 1)) * rsqrtf((float)(deg[d] + 1));
    int p = rowptr[d] + atomicAdd(&cnt[d], 1);
    esrc[p] = s;
    ew[p] = w;
}

// ---- aggregation: 16-lane group per node, bf16x8 (16B) loads ----------------
__global__ __launch_bounds__(256) void agg_gather(
        const int* __restrict__ rowptr, const int* __restrict__ esrc,
        const float* __restrict__ ew, const __bf16* __restrict__ hb,
        __bf16* __restrict__ aggb) {
    const int tid = blockIdx.x * 256 + threadIdx.x;
    const int n = tid >> 4;
    const int l = tid & 15;
    if (n >= NNODES) return;
    int p  = rowptr[n];
    const int pe = rowptr[n + 1];
    float acc[8] = {};
    int   cs0, cs1, cs2, cs3;
    float cw0, cw1, cw2, cw3;
    bool have = (p + 3 < pe);
    if (have) {
        cs0 = esrc[p]; cs1 = esrc[p + 1]; cs2 = esrc[p + 2]; cs3 = esrc[p + 3];
        cw0 = ew[p];   cw1 = ew[p + 1];   cw2 = ew[p + 2];   cw3 = ew[p + 3];
    }
    while (have) {
        int np = p + 4;
        bool nh = (np + 3 < pe);
        int   ns0 = 0, ns1 = 0, ns2 = 0, ns3 = 0;
        float nw0 = 0, nw1 = 0, nw2 = 0, nw3 = 0;
        if (nh) {
            ns0 = esrc[np]; ns1 = esrc[np + 1]; ns2 = esrc[np + 2]; ns3 = esrc[np + 3];
            nw0 = ew[np];   nw1 = ew[np + 1];   nw2 = ew[np + 2];   nw3 = ew[np + 3];
        }
        bf16x8 v0 = *(const bf16x8*)(hb + (size_t)cs0 * DF + l * 8);
        bf16x8 v1 = *(const bf16x8*)(hb + (size_t)cs1 * DF + l * 8);
        bf16x8 v2 = *(const bf16x8*)(hb + (size_t)cs2 * DF + l * 8);
        bf16x8 v3 = *(const bf16x8*)(hb + (size_t)cs3 * DF + l * 8);
#pragma unroll
        for (int j = 0; j < 8; ++j)
            acc[j] += cw0 * (float)v0[j] + cw1 * (float)v1[j]
                    + cw2 * (float)v2[j] + cw3 * (float)v3[j];
        p = np;
        cs0 = ns0; cs1 = ns1; cs2 = ns2; cs3 = ns3;
        cw0 = nw0; cw1 = nw1; cw2 = nw2; cw3 = nw3;
        have = nh;
    }
    for (; p < pe; ++p) {
        int   s0 = esrc[p];
        float w0 = ew[p];
        bf16x8 v0 = *(const bf16x8*)(hb + (size_t)s0 * DF + l * 8);
#pragma unroll
        for (int j = 0; j < 8; ++j) acc[j] += w0 * (float)v0[j];
    }
    bf16x8 o;
#pragma unroll
    for (int j = 0; j < 8; ++j) o[j] = (__bf16)acc[j];
    *(bf16x8*)(aggb + (size_t)n * DF + l * 8) = o;
}

// ---- fused Euler step: out = h + EPS*(kanl(h) + kanc(agg)) -------------------
// R14 structure; changes this round: (1) spline_pack uses unscaled basis
// polynomials (1/6 folded into weights at build time), (2) epilogue fast path
// for the 781/782 blocks with no row masking (skips 32 per-lane v_cmp/exec ops).
__global__ __launch_bounds__(256, 4) void kan_step(
        const float* __restrict__ h,          // f32 state (epilogue read)
        const __bf16* __restrict__ xb,        // bf16 shadow of h (branch L)
        const __bf16* __restrict__ aggb,      // bf16 aggregate (branch C)
        const __bf16* __restrict__ wtl, const __bf16* __restrict__ wtc,
        float* __restrict__ out, __bf16* __restrict__ outb) {
    __shared__ __bf16 Bs[3][128 * 32];       // 3 x 8 KB ring, slot-swizzled rows
    __shared__ __bf16 Xs[64 * 128];          // 16 KB, swizzled 16B granules

    const int tid  = threadIdx.x;
    const int lane = tid & 63;
    const int w    = tid >> 6;               // wave -> rows [w*16, +16)
    const int q    = lane >> 4, l15 = lane & 15;
    const int n0   = blockIdx.x * 64;
    const int myrow = w * 16 + l15;
    const int msw   = myrow & 7;             // Xs swizzle key for this lane

    const int relrow = lane >> 2;
    const int slotx  = (lane & 3) ^ ((relrow >> 1) & 3);  // R10 bank swizzle
    const int r0 = w * 16 + relrow;
    const size_t gb0 = (size_t)r0 * KW + (size_t)slotx * 8;
    const size_t gb1 = gb0 + (size_t)64 * KW;
    const int bslot = (q ^ ((l15 >> 1) & 3)) * 8;   // elems

    const int xrow = tid >> 2, xseg = tid & 3;
    const bool xok = (n0 + xrow) < NNODES;
    const size_t xgoff = (size_t)(n0 + xrow) * DF + xseg * 32;

    f32x4 acc[8] = {};

    auto xs_write = [&](uint4 v0, uint4 v1, uint4 v2, uint4 v3) {
        const int gl = xrow * 16 + xseg * 4;
        const int sw = xrow & 7;
        *(uint4*)&Xs[(size_t)((gl + 0) ^ sw) * 8] = v0;
        *(uint4*)&Xs[(size_t)((gl + 1) ^ sw) * 8] = v1;
        *(uint4*)&Xs[(size_t)((gl + 2) ^ sw) * 8] = v2;
        *(uint4*)&Xs[(size_t)((gl + 3) ^ sw) * 8] = v3;
    };

    auto stageB = [&](int t2, int sb) {
        const __bf16* wtp = (t2 >= 36) ? wtc : wtl;
        const int k0 = ((t2 >= 36) ? t2 - 36 : t2) * 32;
        GLOAD16(wtp + gb0 + k0, &Bs[sb][(w * 16) * 32]);        // rows w*16..+16
        GLOAD16(wtp + gb1 + k0, &Bs[sb][(64 + w * 16) * 32]);   // rows 64+w*16..+16
    };

    auto spline_pack = [&](float x) -> bf16x8 {
        float f  = __builtin_fmaf(x, 2.5f, 5.5f);    // (x+2.2)/0.4
        float fi = floorf(f);
        int  idx = (int)fi;
        float u  = f - fi;
        float u2 = u * u, u3 = u2 * u;
        float om = 1.0f - u;
        // 1/6 pre-folded into the spline weights (prep_fused) -> unscaled basis
        float Wa = u3;
        float Wb = ((-3.0f * u + 3.0f) * u + 3.0f) * u + 1.0f;
        float Wc = (3.0f * u - 6.0f) * u2 + 4.0f;
        float Wd = om * om * om;
        unsigned long p =
              (unsigned long)__builtin_bit_cast(unsigned short, (__bf16)Wd)
            | ((unsigned long)__builtin_bit_cast(unsigned short, (__bf16)Wc) << 16)
            | ((unsigned long)__builtin_bit_cast(unsigned short, (__bf16)Wb) << 32)
            | ((unsigned long)__builtin_bit_cast(unsigned short, (__bf16)Wa) << 48);
        int tt = idx - 3;                            // slot of Wd in [0,8)
        unsigned long lo, hi;
        if (tt >= 0) {
            int s = (tt & 3) * 16;
            unsigned long sv = p << s;
            unsigned long cr = (p >> (63 - s)) >> 1; // == p>>(64-s), s==0 safe
            bool hh = tt >= 4;
            lo = hh ? 0ul : sv;
            hi = hh ? sv : cr;
            if (tt >= 8) { lo = 0; hi = 0; }
        } else {
            int s = (-tt) * 16;
            lo = (tt >= -3) ? (p >> (s & 63)) : 0ul;
            hi = 0;
        }
        ulongx2 r; r[0] = lo; r[1] = hi;
        return __builtin_bit_cast(bf16x8, r);
    };

    auto silu8 = [&](const __bf16* xs) -> bf16x8 {
        bf16x8 v = *(const bf16x8*)xs;
        bf16x8 o;
#pragma unroll
        for (int j = 0; j < 8; ++j) {
            float x = (float)v[j];
            float e = 1.0f + __expf(-x);
            o[j] = (__bf16)(x * __builtin_amdgcn_rcpf(e));   // 1-ulp rcp, bf16-safe
        }
        return o;
    };

    // ---- prologue: both x-tiles loaded now (aggb is ready at launch) ----
    uint4 a0 = {}, a1 = {}, a2 = {}, a3 = {};
    uint4 c0 = {}, c1 = {}, c2 = {}, c3 = {};
    if (xok) {
        const uint4* ga = (const uint4*)(xb + xgoff);
        a0 = ga[0]; a1 = ga[1]; a2 = ga[2]; a3 = ga[3];
        const uint4* gc = (const uint4*)(aggb + xgoff);
        c0 = gc[0]; c1 = gc[1]; c2 = gc[2]; c3 = gc[3];
    }
    xs_write(a0, a1, a2, a3);
    stageB(0, 0);
    stageB(1, 1);
    // "memory" clobber: full compiler memory barrier -> the aggb loads above
    // cannot sink past this point; also orders the Xs ds_writes.
    asm volatile("s_waitcnt lgkmcnt(0)" ::: "memory");

    auto body = [&](int t, int cb, int sb, bool doStage, bool last) {
        if (last) asm volatile("s_waitcnt vmcnt(0)" ::: "memory");
        else      asm volatile("s_waitcnt vmcnt(2)" ::: "memory");  // chunk t staged
        __builtin_amdgcn_s_barrier();
        __builtin_amdgcn_sched_barrier(0);   // nothing crosses the barrier

        if (t == 36) {                       // branch switch: restage x-tile
            xs_write(c0, c1, c2, c3);        // all branch-L Xs reads done (barrier)
            asm volatile("s_waitcnt lgkmcnt(0)" ::: "memory");
            __builtin_amdgcn_s_barrier();
            __builtin_amdgcn_sched_barrier(0);
        }

        if (doStage) stageB(t + 2, sb);      // overwrites buf[(t-1)%3]: safe

        const int ck = (t >= 36) ? t - 36 : t;
        bf16x8 a;
        if (ck < 4) {
            // silu: features [ck*32 + q*8, +8) -> granule myrow*16 + ck*4 + q
            const int g = (myrow * 16 + ck * 4 + q) ^ msw;
            a = silu8(&Xs[(size_t)g * 8]);
        } else {
            const int f = (ck - 4) * 4 + q;  // feature index
            const int g = (myrow * 16 + (f >> 3)) ^ msw;
            unsigned short u0 =
                *(const unsigned short*)&Xs[(size_t)g * 8 + (f & 7)];
            a = spline_pack(__builtin_bit_cast(float, (unsigned)u0 << 16));
        }

        bf16x8 bF[8];
#pragma unroll
        for (int nj = 0; nj < 8; ++nj)
            bF[nj] = *(const bf16x8*)&Bs[cb][(nj * 16 + l15) * 32 + bslot];
#pragma unroll
        for (int nj = 0; nj < 8; ++nj)
            acc[nj] = __builtin_amdgcn_mfma_f32_16x16x32_bf16(a, bF[nj], acc[nj], 0, 0, 0);
    };

    int cb = 0, sb = 2;
#pragma unroll 3
    for (int t = 0; t < 69; ++t) {
        body(t, cb, sb, true, false);
        cb = (cb == 2) ? 0 : cb + 1;
        sb = (sb == 2) ? 0 : sb + 1;
    }
    body(69, 0, 2, true,  false);            // stages chunk 71 -> buf 2
    body(70, 1, 0, false, false);            // vmcnt(2): chunk 70 ready
    body(71, 2, 0, false, true);             // vmcnt(0): final chunk

    // epilogue: Euler; D layout row = q*4+r, col = l15 (m89-verified)
    const bool wxb = (outb != nullptr);      // uniform; final step skips shadow
    if (n0 + 64 <= NNODES) {                 // uniform fast path (781/782 blocks)
#pragma unroll
        for (int nj = 0; nj < 8; ++nj) {
#pragma unroll
            for (int r = 0; r < 4; ++r) {
                size_t idx = (size_t)(n0 + w * 16 + q * 4 + r) * DF + nj * 16 + l15;
                float v = h[idx] + EPS * acc[nj][r];
                out[idx] = v;
                if (wxb) outb[idx] = (__bf16)v;
            }
        }
    } else {
#pragma unroll
        for (int nj = 0; nj < 8; ++nj) {
#pragma unroll
            for (int r = 0; r < 4; ++r) {
                int row = n0 + w * 16 + q * 4 + r;
                int col = nj * 16 + l15;
                if (row < NNODES) {
                    size_t idx = (size_t)row * DF + col;
                    float v = h[idx] + EPS * acc[nj][r];
                    out[idx] = v;
                    if (wxb) outb[idx] = (__bf16)v;
                }
            }
        }
    }
}

extern "C" void kernel_launch(void* const* d_in, const int* in_sizes, int n_in,
                              void* d_out, int out_size, void* d_ws, size_t ws_size,
                              hipStream_t stream) {
    const float* x   = (const float*)d_in[0];
    const int*   ei  = (const int*)d_in[1];     // edge_index [2,E] int32
    const float* bwl = (const float*)d_in[2];
    const float* swl = (const float*)d_in[3];
    const float* bwc = (const float*)d_in[4];
    const float* swc = (const float*)d_in[5];
    float* out = (float*)d_out;

    char* ws = (char*)d_ws;
    int*    deg    = (int*)  (ws + 0);            //   200,000
    int*    cnt    = (int*)  (ws + 200000);       //   200,000 (adjacent: single memset)
    int*    rowptr = (int*)  (ws + 400000);       //   200,004
    int*    bsum   = (int*)  (ws + 600064);       //       784
    int*    esrc   = (int*)  (ws + 601728);       // 3,200,000
    float*  ew     = (float*)(ws + 3801728);      // 3,200,000
    __bf16* xb     = (__bf16*)(ws + 7001728);     // 12,800,000
    __bf16* aggb   = (__bf16*)(ws + 19801728);    // 12,800,000
    __bf16* wtl    = (__bf16*)(ws + 32601728);    //    294,912
    __bf16* wtc    = (__bf16*)(ws + 32896640);    //    294,912  (total ~33.2 MB)

    (void)hipMemsetAsync(deg, 0, 400000, stream);       // deg + cnt
    prep_fused<<<4277, 256, 0, stream>>>(x, ei, bwl, swl, bwc, swc, xb, deg, wtl, wtc);
    scan_part<<<NB, 256, 0, stream>>>(deg, bsum);
    scan_final<<<NB, 256, 0, stream>>>(deg, bsum, rowptr);
    fill_csr<<<3125, 256, 0, stream>>>(ei, deg, rowptr, cnt, esrc, ew);

    const int gemm_grid = (NNODES + 63) / 64;     // 782
    agg_gather<<<3125, 256, 0, stream>>>(rowptr, esrc, ew, xb, aggb);
    kan_step<<<gemm_grid, 256, 0, stream>>>(x, xb, aggb, wtl, wtc, out, xb);
    agg_gather<<<3125, 256, 0, stream>>>(rowptr, esrc, ew, xb, aggb);
    kan_step<<<gemm_grid, 256, 0, stream>>>(out, xb, aggb, wtl, wtc, out, (__bf16*)nullptr);
}